// Round 12
// baseline (324.594 us; speedup 1.0000x reference)
//
#include <hip/hip_runtime.h>
#include <hip/hip_fp16.h>

// GraphEmbedNet: 3-layer GCN, N=50000, E=800000, F=128/128/64.
// R12: (a) agg's csr stream loads marked nontemporal -- the 6.8MB zero-reuse
// stream was competing with the 12.8MB m-buffer for L2 residency during the
// random gather; (b) SORT_ITEMS 2048->4096 halves ghist scan footprint.
// Everything else byte-identical to R11 (297.8us).

#define K_DIM 128
#define SORT_ITEMS 4096   // elements per pass-1 block

typedef unsigned long long u64;
typedef unsigned int u32;

using half8   = __attribute__((ext_vector_type(8))) _Float16;
using floatx4 = __attribute__((ext_vector_type(4))) float;

// ---------------- sort-based CSR build ----------------

// fused: pack edges + self-loops AND per-block 256-bin hist of high byte.
// blocks [nb, nb+nwb): convert W1|W2|W3 fp32 -> fp16 instead.
__global__ void build_hist(const int* __restrict__ row, const int* __restrict__ col,
                           const float* __restrict__ ew, u64* __restrict__ el,
                           u32* __restrict__ ghist, int E, int N, int nb,
                           const float* __restrict__ W1, const float* __restrict__ W2,
                           const float* __restrict__ W3, __half* __restrict__ Wh,
                           int nw1, int nw2, int nw3) {
    const int b = blockIdx.x;
    if (b >= nb) {
        const int i = (b - nb) * 256 + threadIdx.x;
        const int tot = nw1 + nw2 + nw3;
        if (i < tot) {
            float v = (i < nw1) ? W1[i] : (i < nw1 + nw2 ? W2[i - nw1] : W3[i - nw1 - nw2]);
            Wh[i] = __float2half_rn(v);
        }
        return;
    }
    __shared__ u32 bin[256];
    bin[threadIdx.x] = 0;
    __syncthreads();
    const int total = E + N;
    const int base = b * SORT_ITEMS;
    const int end = min(base + SORT_ITEMS, total);
    for (int i = base + threadIdx.x; i < end; i += 256) {
        u64 e;
        if (i < E) {
            e = ((u64)(u32)col[i] << 48) | ((u64)(u32)row[i] << 32)
              | (u64)__float_as_uint(ew[i]);
        } else {
            int v = i - E;
            e = ((u64)(u32)v << 48) | ((u64)(u32)v << 32)
              | (u64)__float_as_uint(1.0f);
        }
        el[i] = e;
        atomicAdd(&bin[(u32)(e >> 56)], 1u);
    }
    __syncthreads();
    ghist[(size_t)threadIdx.x * nb + b] = bin[threadIdx.x];
}

// block d reduces ghist[d*nb .. d*nb+nb) -> dsum[d]
__global__ void digit_sum(const u32* __restrict__ ghist, u32* __restrict__ dsum, int nb) {
    __shared__ u32 s[256];
    const int d = blockIdx.x;
    u32 acc = 0;
    for (int i = threadIdx.x; i < nb; i += 256) acc += ghist[(size_t)d * nb + i];
    s[threadIdx.x] = acc;
    __syncthreads();
    for (int off = 128; off > 0; off >>= 1) {
        if (threadIdx.x < off) s[threadIdx.x] += s[threadIdx.x + off];
        __syncthreads();
    }
    if (threadIdx.x == 0) dsum[d] = s[0];
}

// block d: re-scan dsum in LDS for its digit base (saves a launch), write
// dbase[d] (+[256]), then exclusive-scan its nb block-counts in place.
__global__ void digit_scan(u32* __restrict__ ghist, const u32* __restrict__ dsum,
                           u32* __restrict__ dbase, int nb) {
    __shared__ u32 ds[256];
    __shared__ u32 s[256];
    const int d = blockIdx.x, t = threadIdx.x;
    ds[t] = dsum[t];
    __syncthreads();
    for (int off = 1; off < 256; off <<= 1) {
        u32 u = (t >= off) ? ds[t - off] : 0;
        __syncthreads();
        ds[t] += u;
        __syncthreads();
    }
    u32 carry = (d == 0) ? 0u : ds[d - 1];   // exclusive digit base
    if (t == 0) dbase[d] = carry;
    if (d == 255 && t == 0) dbase[256] = ds[255];
    for (int base = 0; base < nb; base += 256) {
        const int i = base + t;
        const u32 v = (i < nb) ? ghist[(size_t)d * nb + i] : 0;
        s[t] = v;
        __syncthreads();
        for (int off = 1; off < 256; off <<= 1) {
            u32 u = (t >= off) ? s[t - off] : 0;
            __syncthreads();
            s[t] += u;
            __syncthreads();
        }
        if (i < nb) ghist[(size_t)d * nb + i] = carry + s[t] - v;
        carry += s[255];
        __syncthreads();
    }
}

// pass 1 scatter: per-(digit,block) bases from scanned ghist; LDS arrival rank.
__global__ void p1_scatter(const u64* __restrict__ el, const u32* __restrict__ ghist,
                           u64* __restrict__ out, int total, int nb) {
    __shared__ u32 cur[256];
    cur[threadIdx.x] = ghist[(size_t)threadIdx.x * nb + blockIdx.x];
    __syncthreads();
    const int base = blockIdx.x * SORT_ITEMS;
    const int end = min(base + SORT_ITEMS, total);
    for (int i = base + threadIdx.x; i < end; i += 256) {
        u64 e = el[i];
        u32 p = atomicAdd(&cur[(u32)(e >> 56)], 1u);
        out[p] = e;
    }
}

// pass 2: one block per high-byte group; counting sort by low byte. Low-byte
// bins ARE node ids within the group, so this kernel also emits offs[] and
// dinv[] (weighted degree via LDS float atomics during the scatter).
__global__ void p2_sort(const u64* __restrict__ in, u64* __restrict__ out,
                        const u32* __restrict__ dbase,
                        int* __restrict__ offs, float* __restrict__ dinv, int n) {
    const int t = threadIdx.x;
    const int base = (int)dbase[blockIdx.x];
    const int size = (int)dbase[blockIdx.x + 1] - base;
    __shared__ u32 hist[256], cur[256], s[256];
    __shared__ float wsum[256];
    hist[t] = 0;
    wsum[t] = 0.f;
    __syncthreads();
    for (int i = t; i < size; i += 256)
        atomicAdd(&hist[(u32)(in[base + i] >> 48) & 0xFFu], 1u);
    __syncthreads();
    const u32 v = hist[t];
    s[t] = v;
    __syncthreads();
    for (int off = 1; off < 256; off <<= 1) {
        u32 u = (t >= off) ? s[t - off] : 0;
        __syncthreads();
        s[t] += u;
        __syncthreads();
    }
    const u32 mystart = (u32)base + s[t] - v;   // node (blockIdx*256+t)'s run start
    cur[t] = mystart;
    __syncthreads();
    for (int i = t; i < size; i += 256) {
        u64 e = in[base + i];
        u32 lo = (u32)(e >> 48) & 0xFFu;
        u32 p = atomicAdd(&cur[lo], 1u);
        out[p] = e;
        atomicAdd(&wsum[lo], __uint_as_float((u32)(e & 0xFFFFFFFFu)));
    }
    __syncthreads();
    const int node = blockIdx.x * 256 + t;
    if (node < n && v > 0) {
        offs[node] = (int)mystart;
        dinv[node] = rsqrtf(wsum[t]);
        if (node == n - 1) offs[n] = (int)(mystart + v);
    }
}

// ---------------- MFMA GEMM: C[n][o] = half(dinv[n] * sum_k A[n][k] * W[o][k]) ----------------

template <int BN, bool FP32IN>
__global__ __launch_bounds__(256) void mfma_gemm(const void* __restrict__ Ain,
                                                 const __half* __restrict__ Wh,
                                                 const float* __restrict__ dinv,
                                                 __half* __restrict__ C, int nrows) {
    constexpr int NT = BN / 16;
    const int wave = threadIdx.x >> 6;
    const int lane = threadIdx.x & 63;
    const int quad = lane >> 4;
    const int l16  = lane & 15;
    const int row0 = blockIdx.x * 64 + wave * 16;

    int arow = row0 + l16;
    if (arow > nrows - 1) arow = nrows - 1;

    floatx4 acc[NT] = {};

#pragma unroll
    for (int kc = 0; kc < 4; ++kc) {
        const int kof = kc * 32 + quad * 8;
        half8 af;
        if constexpr (FP32IN) {
            const float* ap = (const float*)Ain + (size_t)arow * K_DIM + kof;
            float4 f0 = *(const float4*)ap;
            float4 f1 = *(const float4*)(ap + 4);
            af[0] = (_Float16)f0.x; af[1] = (_Float16)f0.y;
            af[2] = (_Float16)f0.z; af[3] = (_Float16)f0.w;
            af[4] = (_Float16)f1.x; af[5] = (_Float16)f1.y;
            af[6] = (_Float16)f1.z; af[7] = (_Float16)f1.w;
        } else {
            af = *(const half8*)((const __half*)Ain + (size_t)arow * K_DIM + kof);
        }
#pragma unroll
        for (int ct = 0; ct < NT; ++ct) {
            half8 bf = *(const half8*)(Wh + (size_t)(ct * 16 + l16) * K_DIM + kof);
            acc[ct] = __builtin_amdgcn_mfma_f32_16x16x32_f16(af, bf, acc[ct], 0, 0, 0);
        }
    }

    // epilogue: D(row=quad*4+r, col=ct*16+l16)
    float dv[4];
    int grow[4];
    bool ok[4];
#pragma unroll
    for (int r = 0; r < 4; ++r) {
        grow[r] = row0 + quad * 4 + r;
        ok[r] = grow[r] < nrows;
        dv[r] = ok[r] ? dinv[grow[r]] : 0.f;
    }
#pragma unroll
    for (int ct = 0; ct < NT; ++ct) {
        const int colb = ct * 16 + l16;
#pragma unroll
        for (int r = 0; r < 4; ++r)
            if (ok[r])
                C[(size_t)grow[r] * BN + colb] = __float2half_rn(acc[ct][r] * dv[r]);
    }
}

// ---------------- aggregation: out[i] = relu(bias + dinv[i] * sum_e w_e * m[src_e]) ----------------
// m fp16. CSR entry = u64: low 32 = ew bits, bits 32..47 = src row.
// csr loads are nontemporal (zero-reuse stream; keep L2 for m gathers).

template <int D, typename OUT>
__global__ __launch_bounds__(256) void agg_kernel(
    const __half* __restrict__ m, const int* __restrict__ offs,
    const u64* __restrict__ csr, const float* __restrict__ dinv,
    const float* __restrict__ bias, OUT* __restrict__ out, int n) {
    const int wid = threadIdx.x >> 6;
    const int lane = threadIdx.x & 63;
    const int node = (blockIdx.x << 2) + wid;
    if (node >= n) return;
    const int beg = offs[node];
    const int end = offs[node + 1];
    const __half2* mh = (const __half2*)m;   // row stride D/2 half2
    float acc0 = 0.f, acc1 = 0.f;

    if constexpr (D == 128) {
        int k = beg;
        for (; k + 8 <= end; k += 8) {
            u64 e[8];
            float2 f[8];
#pragma unroll
            for (int j = 0; j < 8; ++j) e[j] = __builtin_nontemporal_load(csr + k + j);
#pragma unroll
            for (int j = 0; j < 8; ++j)
                f[j] = __half22float2(mh[(size_t)((u32)(e[j] >> 32) & 0xFFFFu) * 64 + lane]);
#pragma unroll
            for (int j = 0; j < 8; ++j) {
                float w = __uint_as_float((u32)e[j]);
                acc0 = fmaf(w, f[j].x, acc0);
                acc1 = fmaf(w, f[j].y, acc1);
            }
        }
        for (; k < end; ++k) {
            u64 e0 = __builtin_nontemporal_load(csr + k);
            float w0 = __uint_as_float((u32)e0);
            float2 f0 = __half22float2(mh[(size_t)((u32)(e0 >> 32) & 0xFFFFu) * 64 + lane]);
            acc0 = fmaf(w0, f0.x, acc0); acc1 = fmaf(w0, f0.y, acc1);
        }
        const float dv = dinv[node];
        const float2 bv = *(const float2*)(bias + 2 * lane);
        float ox = fmaxf(acc0 * dv + bv.x, 0.f);
        float oy = fmaxf(acc1 * dv + bv.y, 0.f);
        if constexpr (sizeof(OUT) == 2) {
            ((__half2*)out)[(size_t)node * 64 + lane] = __floats2half2_rn(ox, oy);
        } else {
            *(float2*)((float*)out + (size_t)node * 128 + 2 * lane) = make_float2(ox, oy);
        }
    } else {
        // D == 64: lanes 0-31 take even edges, 32-63 odd; feature pair (2sl, 2sl+1)
        const int half = lane >> 5;
        const int sl = lane & 31;
        int k = beg;
        for (; k + 8 <= end; k += 8) {
            u64 e0 = __builtin_nontemporal_load(csr + k + half);
            u64 e1 = __builtin_nontemporal_load(csr + k + 2 + half);
            u64 e2 = __builtin_nontemporal_load(csr + k + 4 + half);
            u64 e3 = __builtin_nontemporal_load(csr + k + 6 + half);
            float2 f0 = __half22float2(mh[(size_t)((u32)(e0 >> 32) & 0xFFFFu) * 32 + sl]);
            float2 f1 = __half22float2(mh[(size_t)((u32)(e1 >> 32) & 0xFFFFu) * 32 + sl]);
            float2 f2 = __half22float2(mh[(size_t)((u32)(e2 >> 32) & 0xFFFFu) * 32 + sl]);
            float2 f3 = __half22float2(mh[(size_t)((u32)(e3 >> 32) & 0xFFFFu) * 32 + sl]);
            float w0 = __uint_as_float((u32)e0), w1 = __uint_as_float((u32)e1);
            float w2 = __uint_as_float((u32)e2), w3 = __uint_as_float((u32)e3);
            acc0 = fmaf(w0, f0.x, acc0); acc1 = fmaf(w0, f0.y, acc1);
            acc0 = fmaf(w1, f1.x, acc0); acc1 = fmaf(w1, f1.y, acc1);
            acc0 = fmaf(w2, f2.x, acc0); acc1 = fmaf(w2, f2.y, acc1);
            acc0 = fmaf(w3, f3.x, acc0); acc1 = fmaf(w3, f3.y, acc1);
        }
        for (; k + 2 <= end; k += 2) {
            u64 e0 = __builtin_nontemporal_load(csr + k + half);
            float w0 = __uint_as_float((u32)e0);
            float2 f0 = __half22float2(mh[(size_t)((u32)(e0 >> 32) & 0xFFFFu) * 32 + sl]);
            acc0 = fmaf(w0, f0.x, acc0); acc1 = fmaf(w0, f0.y, acc1);
        }
        if (k < end && half == 0) {
            u64 e0 = __builtin_nontemporal_load(csr + k);
            float w0 = __uint_as_float((u32)e0);
            float2 f0 = __half22float2(mh[(size_t)((u32)(e0 >> 32) & 0xFFFFu) * 32 + sl]);
            acc0 = fmaf(w0, f0.x, acc0); acc1 = fmaf(w0, f0.y, acc1);
        }
        acc0 += __shfl_xor(acc0, 32);
        acc1 += __shfl_xor(acc1, 32);
        if (half == 0) {
            const float dv = dinv[node];
            const float2 bv = *(const float2*)(bias + 2 * sl);
            float ox = fmaxf(acc0 * dv + bv.x, 0.f);
            float oy = fmaxf(acc1 * dv + bv.y, 0.f);
            *(float2*)((float*)out + (size_t)node * 64 + 2 * sl) = make_float2(ox, oy);
        }
    }
}

// ---------------- launch ----------------

extern "C" void kernel_launch(void* const* d_in, const int* in_sizes, int n_in,
                              void* d_out, int out_size, void* d_ws, size_t ws_size,
                              hipStream_t stream) {
    const float* x  = (const float*)d_in[0];
    const int*   ei = (const int*)d_in[1];   // [2, E] int32
    const float* ew = (const float*)d_in[2];
    const float* W1 = (const float*)d_in[3];
    const float* b1 = (const float*)d_in[4];
    const float* W2 = (const float*)d_in[5];
    const float* b2 = (const float*)d_in[6];
    const float* W3 = (const float*)d_in[7];
    const float* b3 = (const float*)d_in[8];
    float* out = (float*)d_out;

    const int N = in_sizes[0] / K_DIM;      // 50000
    const int E = in_sizes[2];              // 800000
    const int* row = ei;                    // edge_index[0] (source)
    const int* col = ei + E;                // edge_index[1] (target / aggregation)

    const int total = E + N;                         // 850000
    const int nb = (total + SORT_ITEMS - 1) / SORT_ITEMS;   // 208
    const int ngroups = (N + 255) >> 8;              // 196 high-byte groups
    const int NW1 = 128 * 128, NW2 = 128 * 128, NW3 = 64 * 128;
    const int nwb = (NW1 + NW2 + NW3 + 255) / 256;   // 160 weight-convert blocks

    // workspace layout, 8B-aligned sections first
    u64* elA      = (u64*)d_ws;                                // total
    u64* elB      = elA + total;                               // total
    __half* m_buf = (__half*)(elB + total);                    // N*128 fp16
    __half* h_buf = m_buf + (size_t)N * K_DIM;                 // N*128 fp16
    __half* Wh    = h_buf + (size_t)N * K_DIM;                 // 40960 fp16
    u32* ghist    = (u32*)(Wh + NW1 + NW2 + NW3);              // 256*nb
    u32* dsum     = ghist + (size_t)256 * nb;                  // 256
    u32* dbase    = dsum + 256;                                // 257
    int* offs     = (int*)(dbase + 257);                       // N+1
    float* dinv   = (float*)(offs + N + 1);                    // N

    build_hist<<<nb + nwb, 256, 0, stream>>>(row, col, ew, elA, ghist, E, N, nb,
                                             W1, W2, W3, Wh, NW1, NW2, NW3);
    digit_sum<<<256, 256, 0, stream>>>(ghist, dsum, nb);
    digit_scan<<<256, 256, 0, stream>>>(ghist, dsum, dbase, nb);
    p1_scatter<<<nb, 256, 0, stream>>>(elA, ghist, elB, total, nb);
    p2_sort<<<ngroups, 256, 0, stream>>>(elB, elA, dbase, offs, dinv, N);

    const int gemm_blocks = (N + 63) / 64;
    const int agg_blocks = (N + 3) / 4;
    const u64* csr = elA;

    // layer 1: m = fp16(dinv * (x @ W1^T)) ; h = fp16(relu(dinv * agg(m) + b1))
    mfma_gemm<128, true><<<gemm_blocks, 256, 0, stream>>>(x, Wh, dinv, m_buf, N);
    agg_kernel<128, __half><<<agg_blocks, 256, 0, stream>>>(m_buf, offs, csr, dinv, b1, h_buf, N);
    // layer 2
    mfma_gemm<128, false><<<gemm_blocks, 256, 0, stream>>>(h_buf, Wh + NW1, dinv, m_buf, N);
    agg_kernel<128, __half><<<agg_blocks, 256, 0, stream>>>(m_buf, offs, csr, dinv, b2, h_buf, N);
    // layer 3: F_OUT=64, write d_out (fp32) directly
    mfma_gemm<64, false><<<gemm_blocks, 256, 0, stream>>>(h_buf, Wh + NW1 + NW2, dinv, m_buf, N);
    agg_kernel<64, float><<<agg_blocks, 256, 0, stream>>>(m_buf, offs, csr, dinv, b3, out, N);
}

// Round 13
// 297.702 us; speedup vs baseline: 1.0903x; 1.0903x over previous
//
#include <hip/hip_runtime.h>
#include <hip/hip_fp16.h>

// GraphEmbedNet: 3-layer GCN, N=50000, E=800000, F=128/128/64.
// R13: revert R12's nontemporal csr loads (FALSIFIED: csr loads are
// wave-uniform with 8 entries/64B line -- nt defeated intra-wave line reuse,
// 8x csr HBM traffic, agg 33->51us). agg back to R11 byte-identical form.
// SORT_ITEMS=4096 kept (sort-side, independent).

#define K_DIM 128
#define SORT_ITEMS 4096   // elements per pass-1 block

typedef unsigned long long u64;
typedef unsigned int u32;

using half8   = __attribute__((ext_vector_type(8))) _Float16;
using floatx4 = __attribute__((ext_vector_type(4))) float;

// ---------------- sort-based CSR build ----------------

// fused: pack edges + self-loops AND per-block 256-bin hist of high byte.
// blocks [nb, nb+nwb): convert W1|W2|W3 fp32 -> fp16 instead.
__global__ void build_hist(const int* __restrict__ row, const int* __restrict__ col,
                           const float* __restrict__ ew, u64* __restrict__ el,
                           u32* __restrict__ ghist, int E, int N, int nb,
                           const float* __restrict__ W1, const float* __restrict__ W2,
                           const float* __restrict__ W3, __half* __restrict__ Wh,
                           int nw1, int nw2, int nw3) {
    const int b = blockIdx.x;
    if (b >= nb) {
        const int i = (b - nb) * 256 + threadIdx.x;
        const int tot = nw1 + nw2 + nw3;
        if (i < tot) {
            float v = (i < nw1) ? W1[i] : (i < nw1 + nw2 ? W2[i - nw1] : W3[i - nw1 - nw2]);
            Wh[i] = __float2half_rn(v);
        }
        return;
    }
    __shared__ u32 bin[256];
    bin[threadIdx.x] = 0;
    __syncthreads();
    const int total = E + N;
    const int base = b * SORT_ITEMS;
    const int end = min(base + SORT_ITEMS, total);
    for (int i = base + threadIdx.x; i < end; i += 256) {
        u64 e;
        if (i < E) {
            e = ((u64)(u32)col[i] << 48) | ((u64)(u32)row[i] << 32)
              | (u64)__float_as_uint(ew[i]);
        } else {
            int v = i - E;
            e = ((u64)(u32)v << 48) | ((u64)(u32)v << 32)
              | (u64)__float_as_uint(1.0f);
        }
        el[i] = e;
        atomicAdd(&bin[(u32)(e >> 56)], 1u);
    }
    __syncthreads();
    ghist[(size_t)threadIdx.x * nb + b] = bin[threadIdx.x];
}

// block d reduces ghist[d*nb .. d*nb+nb) -> dsum[d]
__global__ void digit_sum(const u32* __restrict__ ghist, u32* __restrict__ dsum, int nb) {
    __shared__ u32 s[256];
    const int d = blockIdx.x;
    u32 acc = 0;
    for (int i = threadIdx.x; i < nb; i += 256) acc += ghist[(size_t)d * nb + i];
    s[threadIdx.x] = acc;
    __syncthreads();
    for (int off = 128; off > 0; off >>= 1) {
        if (threadIdx.x < off) s[threadIdx.x] += s[threadIdx.x + off];
        __syncthreads();
    }
    if (threadIdx.x == 0) dsum[d] = s[0];
}

// block d: re-scan dsum in LDS for its digit base (saves a launch), write
// dbase[d] (+[256]), then exclusive-scan its nb block-counts in place.
__global__ void digit_scan(u32* __restrict__ ghist, const u32* __restrict__ dsum,
                           u32* __restrict__ dbase, int nb) {
    __shared__ u32 ds[256];
    __shared__ u32 s[256];
    const int d = blockIdx.x, t = threadIdx.x;
    ds[t] = dsum[t];
    __syncthreads();
    for (int off = 1; off < 256; off <<= 1) {
        u32 u = (t >= off) ? ds[t - off] : 0;
        __syncthreads();
        ds[t] += u;
        __syncthreads();
    }
    u32 carry = (d == 0) ? 0u : ds[d - 1];   // exclusive digit base
    if (t == 0) dbase[d] = carry;
    if (d == 255 && t == 0) dbase[256] = ds[255];
    for (int base = 0; base < nb; base += 256) {
        const int i = base + t;
        const u32 v = (i < nb) ? ghist[(size_t)d * nb + i] : 0;
        s[t] = v;
        __syncthreads();
        for (int off = 1; off < 256; off <<= 1) {
            u32 u = (t >= off) ? s[t - off] : 0;
            __syncthreads();
            s[t] += u;
            __syncthreads();
        }
        if (i < nb) ghist[(size_t)d * nb + i] = carry + s[t] - v;
        carry += s[255];
        __syncthreads();
    }
}

// pass 1 scatter: per-(digit,block) bases from scanned ghist; LDS arrival rank.
__global__ void p1_scatter(const u64* __restrict__ el, const u32* __restrict__ ghist,
                           u64* __restrict__ out, int total, int nb) {
    __shared__ u32 cur[256];
    cur[threadIdx.x] = ghist[(size_t)threadIdx.x * nb + blockIdx.x];
    __syncthreads();
    const int base = blockIdx.x * SORT_ITEMS;
    const int end = min(base + SORT_ITEMS, total);
    for (int i = base + threadIdx.x; i < end; i += 256) {
        u64 e = el[i];
        u32 p = atomicAdd(&cur[(u32)(e >> 56)], 1u);
        out[p] = e;
    }
}

// pass 2: one block per high-byte group; counting sort by low byte. Low-byte
// bins ARE node ids within the group, so this kernel also emits offs[] and
// dinv[] (weighted degree via LDS float atomics during the scatter).
__global__ void p2_sort(const u64* __restrict__ in, u64* __restrict__ out,
                        const u32* __restrict__ dbase,
                        int* __restrict__ offs, float* __restrict__ dinv, int n) {
    const int t = threadIdx.x;
    const int base = (int)dbase[blockIdx.x];
    const int size = (int)dbase[blockIdx.x + 1] - base;
    __shared__ u32 hist[256], cur[256], s[256];
    __shared__ float wsum[256];
    hist[t] = 0;
    wsum[t] = 0.f;
    __syncthreads();
    for (int i = t; i < size; i += 256)
        atomicAdd(&hist[(u32)(in[base + i] >> 48) & 0xFFu], 1u);
    __syncthreads();
    const u32 v = hist[t];
    s[t] = v;
    __syncthreads();
    for (int off = 1; off < 256; off <<= 1) {
        u32 u = (t >= off) ? s[t - off] : 0;
        __syncthreads();
        s[t] += u;
        __syncthreads();
    }
    const u32 mystart = (u32)base + s[t] - v;   // node (blockIdx*256+t)'s run start
    cur[t] = mystart;
    __syncthreads();
    for (int i = t; i < size; i += 256) {
        u64 e = in[base + i];
        u32 lo = (u32)(e >> 48) & 0xFFu;
        u32 p = atomicAdd(&cur[lo], 1u);
        out[p] = e;
        atomicAdd(&wsum[lo], __uint_as_float((u32)(e & 0xFFFFFFFFu)));
    }
    __syncthreads();
    const int node = blockIdx.x * 256 + t;
    if (node < n && v > 0) {
        offs[node] = (int)mystart;
        dinv[node] = rsqrtf(wsum[t]);
        if (node == n - 1) offs[n] = (int)(mystart + v);
    }
}

// ---------------- MFMA GEMM: C[n][o] = half(dinv[n] * sum_k A[n][k] * W[o][k]) ----------------

template <int BN, bool FP32IN>
__global__ __launch_bounds__(256) void mfma_gemm(const void* __restrict__ Ain,
                                                 const __half* __restrict__ Wh,
                                                 const float* __restrict__ dinv,
                                                 __half* __restrict__ C, int nrows) {
    constexpr int NT = BN / 16;
    const int wave = threadIdx.x >> 6;
    const int lane = threadIdx.x & 63;
    const int quad = lane >> 4;
    const int l16  = lane & 15;
    const int row0 = blockIdx.x * 64 + wave * 16;

    int arow = row0 + l16;
    if (arow > nrows - 1) arow = nrows - 1;

    floatx4 acc[NT] = {};

#pragma unroll
    for (int kc = 0; kc < 4; ++kc) {
        const int kof = kc * 32 + quad * 8;
        half8 af;
        if constexpr (FP32IN) {
            const float* ap = (const float*)Ain + (size_t)arow * K_DIM + kof;
            float4 f0 = *(const float4*)ap;
            float4 f1 = *(const float4*)(ap + 4);
            af[0] = (_Float16)f0.x; af[1] = (_Float16)f0.y;
            af[2] = (_Float16)f0.z; af[3] = (_Float16)f0.w;
            af[4] = (_Float16)f1.x; af[5] = (_Float16)f1.y;
            af[6] = (_Float16)f1.z; af[7] = (_Float16)f1.w;
        } else {
            af = *(const half8*)((const __half*)Ain + (size_t)arow * K_DIM + kof);
        }
#pragma unroll
        for (int ct = 0; ct < NT; ++ct) {
            half8 bf = *(const half8*)(Wh + (size_t)(ct * 16 + l16) * K_DIM + kof);
            acc[ct] = __builtin_amdgcn_mfma_f32_16x16x32_f16(af, bf, acc[ct], 0, 0, 0);
        }
    }

    // epilogue: D(row=quad*4+r, col=ct*16+l16)
    float dv[4];
    int grow[4];
    bool ok[4];
#pragma unroll
    for (int r = 0; r < 4; ++r) {
        grow[r] = row0 + quad * 4 + r;
        ok[r] = grow[r] < nrows;
        dv[r] = ok[r] ? dinv[grow[r]] : 0.f;
    }
#pragma unroll
    for (int ct = 0; ct < NT; ++ct) {
        const int colb = ct * 16 + l16;
#pragma unroll
        for (int r = 0; r < 4; ++r)
            if (ok[r])
                C[(size_t)grow[r] * BN + colb] = __float2half_rn(acc[ct][r] * dv[r]);
    }
}

// ---------------- aggregation: out[i] = relu(bias + dinv[i] * sum_e w_e * m[src_e]) ----------------
// m fp16. CSR entry = u64 as int2: .x = ew bits, .y & 0xFFFF = src row.
// R11 known-good form (normal cached loads).

template <int D, typename OUT>
__global__ __launch_bounds__(256) void agg_kernel(
    const __half* __restrict__ m, const int* __restrict__ offs,
    const int2* __restrict__ csr, const float* __restrict__ dinv,
    const float* __restrict__ bias, OUT* __restrict__ out, int n) {
    const int wid = threadIdx.x >> 6;
    const int lane = threadIdx.x & 63;
    const int node = (blockIdx.x << 2) + wid;
    if (node >= n) return;
    const int beg = offs[node];
    const int end = offs[node + 1];
    const __half2* mh = (const __half2*)m;   // row stride D/2 half2
    float acc0 = 0.f, acc1 = 0.f;

    if constexpr (D == 128) {
        int k = beg;
        for (; k + 8 <= end; k += 8) {
            int2 e[8];
            float2 f[8];
#pragma unroll
            for (int j = 0; j < 8; ++j) e[j] = csr[k + j];
#pragma unroll
            for (int j = 0; j < 8; ++j)
                f[j] = __half22float2(mh[(size_t)(e[j].y & 0xFFFF) * 64 + lane]);
#pragma unroll
            for (int j = 0; j < 8; ++j) {
                float w = __int_as_float(e[j].x);
                acc0 = fmaf(w, f[j].x, acc0);
                acc1 = fmaf(w, f[j].y, acc1);
            }
        }
        for (; k < end; ++k) {
            int2 e0 = csr[k];
            float w0 = __int_as_float(e0.x);
            float2 f0 = __half22float2(mh[(size_t)(e0.y & 0xFFFF) * 64 + lane]);
            acc0 = fmaf(w0, f0.x, acc0); acc1 = fmaf(w0, f0.y, acc1);
        }
        const float dv = dinv[node];
        const float2 bv = *(const float2*)(bias + 2 * lane);
        float ox = fmaxf(acc0 * dv + bv.x, 0.f);
        float oy = fmaxf(acc1 * dv + bv.y, 0.f);
        if constexpr (sizeof(OUT) == 2) {
            ((__half2*)out)[(size_t)node * 64 + lane] = __floats2half2_rn(ox, oy);
        } else {
            *(float2*)((float*)out + (size_t)node * 128 + 2 * lane) = make_float2(ox, oy);
        }
    } else {
        // D == 64: lanes 0-31 take even edges, 32-63 odd; feature pair (2sl, 2sl+1)
        const int half = lane >> 5;
        const int sl = lane & 31;
        int k = beg;
        for (; k + 8 <= end; k += 8) {
            int2 e0 = csr[k + half], e1 = csr[k + 2 + half];
            int2 e2 = csr[k + 4 + half], e3 = csr[k + 6 + half];
            float2 f0 = __half22float2(mh[(size_t)(e0.y & 0xFFFF) * 32 + sl]);
            float2 f1 = __half22float2(mh[(size_t)(e1.y & 0xFFFF) * 32 + sl]);
            float2 f2 = __half22float2(mh[(size_t)(e2.y & 0xFFFF) * 32 + sl]);
            float2 f3 = __half22float2(mh[(size_t)(e3.y & 0xFFFF) * 32 + sl]);
            float w0 = __int_as_float(e0.x), w1 = __int_as_float(e1.x);
            float w2 = __int_as_float(e2.x), w3 = __int_as_float(e3.x);
            acc0 = fmaf(w0, f0.x, acc0); acc1 = fmaf(w0, f0.y, acc1);
            acc0 = fmaf(w1, f1.x, acc0); acc1 = fmaf(w1, f1.y, acc1);
            acc0 = fmaf(w2, f2.x, acc0); acc1 = fmaf(w2, f2.y, acc1);
            acc0 = fmaf(w3, f3.x, acc0); acc1 = fmaf(w3, f3.y, acc1);
        }
        for (; k + 2 <= end; k += 2) {
            int2 e0 = csr[k + half];
            float w0 = __int_as_float(e0.x);
            float2 f0 = __half22float2(mh[(size_t)(e0.y & 0xFFFF) * 32 + sl]);
            acc0 = fmaf(w0, f0.x, acc0); acc1 = fmaf(w0, f0.y, acc1);
        }
        if (k < end && half == 0) {
            int2 e0 = csr[k];
            float w0 = __int_as_float(e0.x);
            float2 f0 = __half22float2(mh[(size_t)(e0.y & 0xFFFF) * 32 + sl]);
            acc0 = fmaf(w0, f0.x, acc0); acc1 = fmaf(w0, f0.y, acc1);
        }
        acc0 += __shfl_xor(acc0, 32);
        acc1 += __shfl_xor(acc1, 32);
        if (half == 0) {
            const float dv = dinv[node];
            const float2 bv = *(const float2*)(bias + 2 * sl);
            float ox = fmaxf(acc0 * dv + bv.x, 0.f);
            float oy = fmaxf(acc1 * dv + bv.y, 0.f);
            *(float2*)((float*)out + (size_t)node * 64 + 2 * sl) = make_float2(ox, oy);
        }
    }
}

// ---------------- launch ----------------

extern "C" void kernel_launch(void* const* d_in, const int* in_sizes, int n_in,
                              void* d_out, int out_size, void* d_ws, size_t ws_size,
                              hipStream_t stream) {
    const float* x  = (const float*)d_in[0];
    const int*   ei = (const int*)d_in[1];   // [2, E] int32
    const float* ew = (const float*)d_in[2];
    const float* W1 = (const float*)d_in[3];
    const float* b1 = (const float*)d_in[4];
    const float* W2 = (const float*)d_in[5];
    const float* b2 = (const float*)d_in[6];
    const float* W3 = (const float*)d_in[7];
    const float* b3 = (const float*)d_in[8];
    float* out = (float*)d_out;

    const int N = in_sizes[0] / K_DIM;      // 50000
    const int E = in_sizes[2];              // 800000
    const int* row = ei;                    // edge_index[0] (source)
    const int* col = ei + E;                // edge_index[1] (target / aggregation)

    const int total = E + N;                         // 850000
    const int nb = (total + SORT_ITEMS - 1) / SORT_ITEMS;   // 208
    const int ngroups = (N + 255) >> 8;              // 196 high-byte groups
    const int NW1 = 128 * 128, NW2 = 128 * 128, NW3 = 64 * 128;
    const int nwb = (NW1 + NW2 + NW3 + 255) / 256;   // 160 weight-convert blocks

    // workspace layout, 8B-aligned sections first
    u64* elA      = (u64*)d_ws;                                // total
    u64* elB      = elA + total;                               // total
    __half* m_buf = (__half*)(elB + total);                    // N*128 fp16
    __half* h_buf = m_buf + (size_t)N * K_DIM;                 // N*128 fp16
    __half* Wh    = h_buf + (size_t)N * K_DIM;                 // 40960 fp16
    u32* ghist    = (u32*)(Wh + NW1 + NW2 + NW3);              // 256*nb
    u32* dsum     = ghist + (size_t)256 * nb;                  // 256
    u32* dbase    = dsum + 256;                                // 257
    int* offs     = (int*)(dbase + 257);                       // N+1
    float* dinv   = (float*)(offs + N + 1);                    // N

    build_hist<<<nb + nwb, 256, 0, stream>>>(row, col, ew, elA, ghist, E, N, nb,
                                             W1, W2, W3, Wh, NW1, NW2, NW3);
    digit_sum<<<256, 256, 0, stream>>>(ghist, dsum, nb);
    digit_scan<<<256, 256, 0, stream>>>(ghist, dsum, dbase, nb);
    p1_scatter<<<nb, 256, 0, stream>>>(elA, ghist, elB, total, nb);
    p2_sort<<<ngroups, 256, 0, stream>>>(elB, elA, dbase, offs, dinv, N);

    const int gemm_blocks = (N + 63) / 64;
    const int agg_blocks = (N + 3) / 4;
    const int2* csr = (const int2*)elA;

    // layer 1: m = fp16(dinv * (x @ W1^T)) ; h = fp16(relu(dinv * agg(m) + b1))
    mfma_gemm<128, true><<<gemm_blocks, 256, 0, stream>>>(x, Wh, dinv, m_buf, N);
    agg_kernel<128, __half><<<agg_blocks, 256, 0, stream>>>(m_buf, offs, csr, dinv, b1, h_buf, N);
    // layer 2
    mfma_gemm<128, false><<<gemm_blocks, 256, 0, stream>>>(h_buf, Wh + NW1, dinv, m_buf, N);
    agg_kernel<128, __half><<<agg_blocks, 256, 0, stream>>>(m_buf, offs, csr, dinv, b2, h_buf, N);
    // layer 3: F_OUT=64, write d_out (fp32) directly
    mfma_gemm<64, false><<<gemm_blocks, 256, 0, stream>>>(h_buf, Wh + NW1 + NW2, dinv, m_buf, N);
    agg_kernel<64, float><<<agg_blocks, 256, 0, stream>>>(m_buf, offs, csr, dinv, b3, out, N);
}